// Round 7
// baseline (226.215 us; speedup 1.0000x reference)
//
#include <hip/hip_runtime.h>
#include <cmath>

// ---------------------------------------------------------------------------
// SwinV2-style window attention, f16-MFMA implementation.  Round 7.
//
// R6->R7:
//  * attn: restore occupancy.  Block = 256 thr (4 waves); wave owns 32
//    q-rows = ONE image row (ih constant per wave).  Grid (8,8,16) = 1024
//    blocks = 4 blocks/CU = 16 waves/CU (was 8).  Still barrier-free K-loop
//    (K/V direct from global, pa per-wave, one barrier total for bias slice).
//  * prep_w deleted: qkv/proj stage fp32 weights straight from inputs,
//    folding +I (qkv) and f16 conversion into the LDS store; biases read
//    directly from global.
// ---------------------------------------------------------------------------

typedef _Float16 half_t;
typedef __attribute__((ext_vector_type(4))) _Float16 half4;
typedef __attribute__((ext_vector_type(8))) _Float16 half8;
typedef __attribute__((ext_vector_type(4))) float float4v;

static __device__ __forceinline__ float4v mfma16(half8 a, half8 b, float4v c) {
  return __builtin_amdgcn_mfma_f32_16x16x32_f16(a, b, c, 0, 0, 0);
}

struct PtrArr8 { const float* p[8]; };

// ---------------------------------------------------------------------------
// bias_mlp: tabh2[h][p] = 16*sigmoid(mlp(...))*log2e + c14(h), 63x63 grid.
// c14(h) = 14 - (scale_h + 16)*log2e; makes attn P~ = exp2(mfma result).
// ---------------------------------------------------------------------------
__global__ __launch_bounds__(256) void bias_mlp(const float* __restrict__ w1,
                                                const float* __restrict__ b1,
                                                const float* __restrict__ w2,
                                                const float* __restrict__ ls,
                                                float* __restrict__ tabh2) {
  __shared__ float sw1[256];
  __shared__ float sb1[128];
  __shared__ float sw2[1024];
  int t = threadIdx.x;
  sw1[t] = w1[t];
  if (t < 128) sb1[t] = b1[t];
  for (int i = t; i < 1024; i += 256) sw2[i] = w2[i];
  __syncthreads();
  int p = blockIdx.x * 256 + t;
  if (p >= 3969) return;
  int ph = p / 63, pw = p % 63;
  float t0 = (float)(ph - 31) * (3.2f / 31.0f);
  float t1 = (float)(pw - 31) * (3.2f / 31.0f);
  t0 = copysignf(1.0f - __expf(-fabsf(t0)), t0);
  t1 = copysignf(1.0f - __expf(-fabsf(t1)), t1);
  float acc[8];
#pragma unroll
  for (int hh = 0; hh < 8; hh++) acc[hh] = 0.0f;
  for (int j = 0; j < 128; j++) {
    float hj = fmaxf(0.0f, t0 * sw1[2 * j] + t1 * sw1[2 * j + 1] + sb1[j]);
#pragma unroll
    for (int hh = 0; hh < 8; hh++) acc[hh] += hj * sw2[hh * 128 + j];
  }
  const float L2E = 1.44269504f;
#pragma unroll
  for (int hh = 0; hh < 8; hh++) {
    float scale = __expf(fminf(ls[hh], 4.6051702f));
    float c14 = 14.0f - (scale + 16.0f) * L2E;
    float bias = 16.0f / (1.0f + __expf(-acc[hh]));
    tabh2[hh * 3969 + p] = bias * L2E + c14;
  }
}

// ---------------------------------------------------------------------------
// qkv_mfma: 3 fused linears for one half (residual folded into W on the
// fly), per-head q/k norm; q scaled by scale*log2e.  grid (256,2) x 256.
// W staged fp32->f16 (+I) into LDS (stride 136).
// ---------------------------------------------------------------------------
__global__ __launch_bounds__(256) void qkv_mfma(
    const float* __restrict__ x, PtrArr8 wsrc, PtrArr8 bsrc,
    const float* __restrict__ lscale, half_t* __restrict__ qf,
    half_t* __restrict__ kf, half_t* __restrict__ vf) {
  __shared__ half_t wb[128 * 136];  // weight tile, padded
  __shared__ half_t tbuf[128 * 68]; // transpose buffer
  int t = threadIdx.x;
  int lane = t & 63, wv = t >> 6, l = lane & 15, quad = lane >> 4;
  int hf = blockIdx.y;
  int m0 = blockIdx.x * 64;
  int b = m0 >> 10, n0 = m0 & 1023;

  half8 afr[4];
  {
    const float* xb = x + (size_t)b * 256 * 1024 + n0 + wv * 16 + l;
#pragma unroll
    for (int ks = 0; ks < 4; ks++) {
      int kbase = hf * 128 + ks * 32 + quad * 8;
      half8 a;
#pragma unroll
      for (int j = 0; j < 8; j++)
        a[j] = (half_t)xb[(size_t)(kbase + j) * 1024];
      afr[ks] = a;
    }
  }

  for (int op = 0; op < 3; op++) {
    int combo = op * 2 + hf;
    const float* wg = nullptr;
    const float* bg = nullptr;
#pragma unroll
    for (int i = 0; i < 6; i++)
      if (i == combo) { wg = wsrc.p[i]; bg = bsrc.p[i]; }
    __syncthreads();
    // stage W fp32 -> f16 (+I) into LDS, coalesced float4 loads
#pragma unroll
    for (int i = 0; i < 16; i++) {
      int flat = (t + 256 * i) * 4;
      int row = flat >> 7, col = flat & 127;
      float4 w = *(const float4*)(wg + flat);
      half4 h;
      h[0] = (half_t)(w.x + (col == row ? 1.0f : 0.0f));
      h[1] = (half_t)(w.y + (col + 1 == row ? 1.0f : 0.0f));
      h[2] = (half_t)(w.z + (col + 2 == row ? 1.0f : 0.0f));
      h[3] = (half_t)(w.w + (col + 3 == row ? 1.0f : 0.0f));
      *(half4*)(wb + row * 136 + col) = h;
    }
    __syncthreads();

    float4v acc[8];
#pragma unroll
    for (int ng = 0; ng < 8; ng++) {
      float4v c = {0.f, 0.f, 0.f, 0.f};
#pragma unroll
      for (int ks = 0; ks < 4; ks++) {
        half8 bfrag =
            *(const half8*)(wb + (ng * 16 + l) * 136 + ks * 32 + quad * 8);
        c = mfma16(afr[ks], bfrag, c);
      }
      acc[ng] = c;
    }
#pragma unroll
    for (int ng = 0; ng < 8; ng++) {
      float bb = bg[ng * 16 + l];
#pragma unroll
      for (int r2 = 0; r2 < 4; r2++) acc[ng][r2] += bb;
    }
    if (op < 2) {
#pragma unroll
      for (int hg = 0; hg < 4; hg++) {
        float sc = 1.0f;
        if (op == 0)
          sc = __expf(fminf(lscale[hf * 4 + hg], 4.6051702f)) * 1.44269504f;
#pragma unroll
        for (int r2 = 0; r2 < 4; r2++) {
          float ss = acc[2 * hg][r2] * acc[2 * hg][r2] +
                     acc[2 * hg + 1][r2] * acc[2 * hg + 1][r2];
          ss += __shfl_xor(ss, 1, 64);
          ss += __shfl_xor(ss, 2, 64);
          ss += __shfl_xor(ss, 4, 64);
          ss += __shfl_xor(ss, 8, 64);
          float rn = sc / fmaxf(sqrtf(ss), 1e-12f);
          acc[2 * hg][r2] *= rn;
          acc[2 * hg + 1][r2] *= rn;
        }
      }
#pragma unroll
      for (int ng = 0; ng < 8; ng++)
#pragma unroll
        for (int r2 = 0; r2 < 4; r2++)
          tbuf[(wv * 16 + quad * 4 + r2) * 132 + ng * 16 + l] =
              (half_t)acc[ng][r2];
      __syncthreads();
      half_t* dst = (op == 0) ? qf : kf;
#pragma unroll
      for (int i = 0; i < 4; i++) {
        int idx = t + 256 * i;
        int row = idx >> 4, colc = (idx & 15) * 8;
        half8 vv = *(const half8*)(tbuf + row * 132 + colc);
        int head = hf * 4 + (colc >> 5), d = colc & 31;
        *(half8*)(dst + (((size_t)b * 8 + head) * 1024 + n0 + row) * 32 + d) =
            vv;
      }
    } else {
#pragma unroll
      for (int ng = 0; ng < 8; ng++) {
        int col = ng * 16 + l;
        half4 hv;
#pragma unroll
        for (int r2 = 0; r2 < 4; r2++) hv[r2] = (half_t)acc[ng][r2];
        *(half4*)(tbuf + col * 68 + wv * 16 + quad * 4) = hv;
      }
      __syncthreads();
#pragma unroll
      for (int i = 0; i < 16; i++) {
        int idx = t + 256 * i;
        int col = idx >> 5, rp = idx & 31;
        unsigned int val = *(const unsigned int*)(tbuf + col * 68 + rp * 2);
        int head = hf * 4 + (col >> 5);
        int d = col & 31;
        *(unsigned int*)((char*)vf +
                         (((((size_t)b * 8 + head) * 32 + d) * 1024) + n0 +
                          rp * 2) * 2) = val;
      }
    }
  }
}

// ---------------------------------------------------------------------------
// attn_mfma: barrier-free flash attention, high occupancy.
// grid (8 q-octs, 8 heads, 16 batch) x 256 (4 waves).  Wave wv owns 32
// q-rows = one image row (ih = qo*4+wv, const).  Strips s in {0,1} of 16.
// K/V fragments direct from global (L2-hot); pa per-wave; ONE barrier.
// P~ = exp2(QK + biastab), all scales pre-folded upstream.
// ---------------------------------------------------------------------------
__global__ __launch_bounds__(256) void attn_mfma(
    const half_t* __restrict__ qf, const half_t* __restrict__ kf,
    const half_t* __restrict__ vf, const float* __restrict__ tabh2,
    half_t* __restrict__ ao) {
  __shared__ float sb2[35 * 63];      // bias slice: dih-local in [0,35)
  __shared__ half_t pa[4 * 16 * 80];  // per-wave P~ [qrow][key], stride 80

  int t = threadIdx.x;
  int lane = t & 63, wv = t >> 6, l = lane & 15, quad = lane >> 4;
  int qo = blockIdx.x, h = blockIdx.y, b = blockIdx.z;
  size_t bh = (size_t)b * 8 + h;
  const half_t* kbase = kf + bh * 1024 * 32;
  const half_t* vbase = vf + bh * 32 * 1024;

  // stage bias slice: dih_global in [qo*4, qo*4+35)
  for (int i = t; i < 2205; i += 256)
    sb2[i] = tabh2[h * 3969 + qo * 252 + i];

  int row0 = qo * 128 + wv * 32;
  half8 qfr[2];
#pragma unroll
  for (int s = 0; s < 2; s++)
    qfr[s] =
        *(const half8*)(qf + (bh * 1024 + row0 + s * 16 + l) * 32 + quad * 8);

  float4v o0[2], o1[2];
  float run_l[2];
#pragma unroll
  for (int s = 0; s < 2; s++) {
    o0[s] = (float4v){0.f, 0.f, 0.f, 0.f};
    o1[s] = (float4v){0.f, 0.f, 0.f, 0.f};
    run_l[s] = 0.0f;
  }
  half_t* paw = pa + wv * 16 * 80;
  __syncthreads();  // the ONLY barrier

#pragma unroll 2
  for (int kt = 0; kt < 16; kt++) {
    half8 kfr[4], v0fr[2], v1fr[2];
#pragma unroll
    for (int nt = 0; nt < 4; nt++)
      kfr[nt] =
          *(const half8*)(kbase + (kt * 64 + nt * 16 + l) * 32 + quad * 8);
#pragma unroll
    for (int ks = 0; ks < 2; ks++) {
      v0fr[ks] = *(const half8*)(vbase + l * 1024 + kt * 64 + ks * 32 +
                                 quad * 8);
      v1fr[ks] = *(const half8*)(vbase + (16 + l) * 1024 + kt * 64 + ks * 32 +
                                 quad * 8);
    }
#pragma unroll
    for (int s = 0; s < 2; s++) {
      float4v sres[4];
#pragma unroll
      for (int nt = 0; nt < 4; nt++) {
        int base = (wv - 2 * kt - (nt >> 1) + 31) * 63 + s * 16 + l + 31 -
                   (nt & 1) * 16 - quad * 4;
        float4v c;
        c[0] = sb2[base];
        c[1] = sb2[base - 1];
        c[2] = sb2[base - 2];
        c[3] = sb2[base - 3];
        sres[nt] = mfma16(kfr[nt], qfr[s], c);
      }
#pragma unroll
      for (int nt = 0; nt < 4; nt++) {
        half4 ph;
#pragma unroll
        for (int r2 = 0; r2 < 4; r2++) {
          float p = exp2f(sres[nt][r2]);
          run_l[s] += p;
          ph[r2] = (half_t)p;
        }
        *(half4*)(paw + l * 80 + nt * 16 + quad * 4) = ph;
      }
#pragma unroll
      for (int ks = 0; ks < 2; ks++) {
        half8 pfr = *(const half8*)(paw + l * 80 + ks * 32 + quad * 8);
        o0[s] = mfma16(pfr, v0fr[ks], o0[s]);
        o1[s] = mfma16(pfr, v1fr[ks], o1[s]);
      }
    }
  }

#pragma unroll
  for (int s = 0; s < 2; s++) {
    float rl = run_l[s];
    rl += __shfl_xor(rl, 16, 64);
    rl += __shfl_xor(rl, 32, 64);
    float rli = 1.0f / rl;
#pragma unroll
    for (int r2 = 0; r2 < 4; r2++) {
      float linv = __shfl(rli, 20 * quad + r2, 64);
      size_t rowaddr =
          ((size_t)b * 1024 + row0 + s * 16 + quad * 4 + r2) * 256 + h * 32;
      ao[rowaddr + l] = (half_t)(o0[s][r2] * linv);
      ao[rowaddr + 16 + l] = (half_t)(o1[s][r2] * linv);
    }
  }
}

// ---------------------------------------------------------------------------
// proj_mfma: output projection for one half, fp32 out [b][ch][n] via LDS
// transpose.  grid (256, 2) x 256.  W staged fp32->f16 in LDS.
// ---------------------------------------------------------------------------
__global__ __launch_bounds__(256) void proj_mfma(
    const half_t* __restrict__ ao, PtrArr8 wsrc, PtrArr8 bsrc,
    float* __restrict__ out) {
  __shared__ half_t wb[128 * 136];
  __shared__ float yt[128 * 68];
  int t = threadIdx.x;
  int lane = t & 63, wv = t >> 6, l = lane & 15, quad = lane >> 4;
  int hf = blockIdx.y;
  int m0 = blockIdx.x * 64;
  int b = m0 >> 10, n0 = m0 & 1023;

  const float* wg = hf ? wsrc.p[7] : wsrc.p[6];
  const float* bg = hf ? bsrc.p[7] : bsrc.p[6];
  // stage W fp32 -> f16
#pragma unroll
  for (int i = 0; i < 16; i++) {
    int flat = (t + 256 * i) * 4;
    int row = flat >> 7, col = flat & 127;
    float4 w = *(const float4*)(wg + flat);
    half4 h;
    h[0] = (half_t)w.x;
    h[1] = (half_t)w.y;
    h[2] = (half_t)w.z;
    h[3] = (half_t)w.w;
    *(half4*)(wb + row * 136 + col) = h;
  }

  half8 afr[4];
  const half_t* ab =
      ao + ((size_t)m0 + wv * 16 + l) * 256 + hf * 128 + quad * 8;
#pragma unroll
  for (int ks = 0; ks < 4; ks++) afr[ks] = *(const half8*)(ab + ks * 32);
  __syncthreads();

#pragma unroll
  for (int ng = 0; ng < 8; ng++) {
    float4v c = {0.f, 0.f, 0.f, 0.f};
#pragma unroll
    for (int ks = 0; ks < 4; ks++)
      c = mfma16(afr[ks],
                 *(const half8*)(wb + (ng * 16 + l) * 136 + ks * 32 +
                                 quad * 8),
                 c);
    float bb = bg[ng * 16 + l];
#pragma unroll
    for (int r2 = 0; r2 < 4; r2++) c[r2] += bb;
    *(float4v*)(yt + (ng * 16 + l) * 68 + wv * 16 + quad * 4) = c;
  }
  __syncthreads();
#pragma unroll
  for (int i = 0; i < 8; i++) {
    int idx = t + 256 * i;
    int col = idx >> 4, rg = idx & 15;
    float4v vv = *(const float4v*)(yt + col * 68 + rg * 4);
    *(float4v*)(out + ((size_t)b * 256 + hf * 128 + col) * 1024 + n0 +
                rg * 4) = vv;
  }
}

// ---------------------------------------------------------------------------
extern "C" void kernel_launch(void* const* d_in, const int* in_sizes, int n_in,
                              void* d_out, int out_size, void* d_ws,
                              size_t ws_size, hipStream_t stream) {
  (void)in_sizes; (void)n_in; (void)out_size; (void)ws_size;
  const float* x = (const float*)d_in[0];

  half_t* ws = (half_t*)d_ws;
  half_t* qfp = ws;                    // [16][8][1024][32] f16
  half_t* kfp = ws + 4194304;          // [16][8][1024][32] f16
  half_t* vfp = ws + 8388608;          // [16][8][32][1024] f16 (transposed)
  half_t* aop = ws + 12582912;         // [16384][256] f16
  float* tabh2 = (float*)((char*)d_ws + 33816576);  // [8][3969] f32

  PtrArr8 wsrc, bsrc;
  const int widx[8] = {1, 3, 5, 7, 9, 11, 13, 15};
  for (int i = 0; i < 8; i++) {
    wsrc.p[i] = (const float*)d_in[widx[i]];
    bsrc.p[i] = (const float*)d_in[widx[i] + 1];
  }

  bias_mlp<<<16, 256, 0, stream>>>((const float*)d_in[18],
                                   (const float*)d_in[19],
                                   (const float*)d_in[20],
                                   (const float*)d_in[17], tabh2);
  qkv_mfma<<<dim3(256, 2), 256, 0, stream>>>(x, wsrc, bsrc,
                                             (const float*)d_in[17], qfp, kfp,
                                             vfp);
  attn_mfma<<<dim3(8, 8, 16), 256, 0, stream>>>(qfp, kfp, vfp, tabh2, aop);
  proj_mfma<<<dim3(256, 2), 256, 0, stream>>>(aop, wsrc, bsrc, (float*)d_out);
}

// Round 8
// 188.126 us; speedup vs baseline: 1.2025x; 1.2025x over previous
//
#include <hip/hip_runtime.h>
#include <cmath>

// ---------------------------------------------------------------------------
// SwinV2-style window attention, f16-MFMA implementation.  Round 8.
//
// R7->R8:
//  * prep_w writes weights PRE-FRAGMENTED in MFMA B-layout
//    [combo][ng][ks][lane][8]: qkv/proj load B-frags as single contiguous
//    1KB wave loads (global_load_dwordx4).  No W LDS, no W barriers.
//  * qkv/proj: 32-row tiles, waves split (2 row-strips x 2 col-halves):
//    grid 1024 = 4 blocks/CU, LDS only for the epilogue transpose.
//  * attn: 1-D grid, id = qo*128 + bh -> blocks sharing (b,h) are congruent
//    mod 8 -> same XCD -> K/V stay L2-resident (2 MB/XCD).
// ---------------------------------------------------------------------------

typedef _Float16 half_t;
typedef __attribute__((ext_vector_type(4))) _Float16 half4;
typedef __attribute__((ext_vector_type(8))) _Float16 half8;
typedef __attribute__((ext_vector_type(4))) float float4v;

static __device__ __forceinline__ float4v mfma16(half8 a, half8 b, float4v c) {
  return __builtin_amdgcn_mfma_f32_16x16x32_f16(a, b, c, 0, 0, 0);
}

struct PtrArr8 { const float* p[8]; };

// ---------------------------------------------------------------------------
// prep_w: fp32 W -> f16 (+I for qkv), PRE-FRAGMENTED B-layout:
// wf[y*16384 + ((ng*4+ks)*64 + quad*16 + l)*8 + (k&7)] = W[j=ng*16+l][k](+I)
// grid (16, 8) x 256.  Biases packed to bws[y][128].
// ---------------------------------------------------------------------------
__global__ __launch_bounds__(256) void prep_w(PtrArr8 wsrc, PtrArr8 bsrc,
                                              half_t* __restrict__ wf,
                                              float* __restrict__ bws) {
  int y = blockIdx.y;
  const float* src = nullptr;
  const float* bs = nullptr;
#pragma unroll
  for (int i = 0; i < 8; i++)
    if (i == y) { src = wsrc.p[i]; bs = bsrc.p[i]; }
  int flat = (blockIdx.x * 256 + threadIdx.x) * 4;
  float4 w = *(const float4*)(src + flat);
  int j = flat >> 7, k = flat & 127;
  if (y < 6) {
    if (k == j)     w.x += 1.0f;
    if (k + 1 == j) w.y += 1.0f;
    if (k + 2 == j) w.z += 1.0f;
    if (k + 3 == j) w.w += 1.0f;
  }
  half4 h;
  h[0] = (half_t)w.x;
  h[1] = (half_t)w.y;
  h[2] = (half_t)w.z;
  h[3] = (half_t)w.w;
  int ng = j >> 4, l = j & 15, ks = k >> 5, quad = (k >> 3) & 3, o8 = k & 7;
  *(half4*)(wf + y * 16384 + ((ng * 4 + ks) * 64 + quad * 16 + l) * 8 + o8) =
      h;
  if (blockIdx.x == 0 && threadIdx.x < 128)
    bws[y * 128 + threadIdx.x] = bs[threadIdx.x];
}

// ---------------------------------------------------------------------------
// bias_mlp: tabh2[h][p] = 16*sigmoid(mlp(...))*log2e + c14(h), 63x63 grid.
// c14(h) = 14 - (scale_h + 16)*log2e; makes attn P~ = exp2(mfma result).
// ---------------------------------------------------------------------------
__global__ __launch_bounds__(256) void bias_mlp(const float* __restrict__ w1,
                                                const float* __restrict__ b1,
                                                const float* __restrict__ w2,
                                                const float* __restrict__ ls,
                                                float* __restrict__ tabh2) {
  __shared__ float sw1[256];
  __shared__ float sb1[128];
  __shared__ float sw2[1024];
  int t = threadIdx.x;
  sw1[t] = w1[t];
  if (t < 128) sb1[t] = b1[t];
  for (int i = t; i < 1024; i += 256) sw2[i] = w2[i];
  __syncthreads();
  int p = blockIdx.x * 256 + t;
  if (p >= 3969) return;
  int ph = p / 63, pw = p % 63;
  float t0 = (float)(ph - 31) * (3.2f / 31.0f);
  float t1 = (float)(pw - 31) * (3.2f / 31.0f);
  t0 = copysignf(1.0f - __expf(-fabsf(t0)), t0);
  t1 = copysignf(1.0f - __expf(-fabsf(t1)), t1);
  float acc[8];
#pragma unroll
  for (int hh = 0; hh < 8; hh++) acc[hh] = 0.0f;
  for (int j = 0; j < 128; j++) {
    float hj = fmaxf(0.0f, t0 * sw1[2 * j] + t1 * sw1[2 * j + 1] + sb1[j]);
#pragma unroll
    for (int hh = 0; hh < 8; hh++) acc[hh] += hj * sw2[hh * 128 + j];
  }
  const float L2E = 1.44269504f;
#pragma unroll
  for (int hh = 0; hh < 8; hh++) {
    float scale = __expf(fminf(ls[hh], 4.6051702f));
    float c14 = 14.0f - (scale + 16.0f) * L2E;
    float bias = 16.0f / (1.0f + __expf(-acc[hh]));
    tabh2[hh * 3969 + p] = bias * L2E + c14;
  }
}

// ---------------------------------------------------------------------------
// qkv_mfma: 3 fused linears (residual folded into W), per-head q/k norm,
// q scaled by scale*log2e.  grid (512 rowtiles-of-32, 2 hf) x 256.
// Wave (rw,cw): rows rw*16..+15, cols cw*64..+63.  W-frags direct from
// global pre-fragmented layout (1KB contiguous wave loads).  LDS only for
// the epilogue transpose.
// ---------------------------------------------------------------------------
__global__ __launch_bounds__(256, 4) void qkv_mfma(
    const float* __restrict__ x, const half_t* __restrict__ wfrag,
    const float* __restrict__ lscale, const float* __restrict__ bws,
    half_t* __restrict__ qf, half_t* __restrict__ kf,
    half_t* __restrict__ vf) {
  __shared__ half_t tbuf[4608];  // q/k: [32][136]; v: [128][36]
  int t = threadIdx.x;
  int lane = t & 63, wv = t >> 6, l = lane & 15, quad = lane >> 4;
  int rw = wv & 1, cw = wv >> 1;
  int hf = blockIdx.y;
  int m0 = blockIdx.x * 32;
  int b = m0 >> 10, n0 = m0 & 1023;

  // A fragments: 16 rows (rw strip), this half's 128 channels.
  half8 afr[4];
  {
    const float* xb =
        x + ((size_t)b * 256 + hf * 128) * 1024 + n0 + rw * 16 + l;
#pragma unroll
    for (int ks = 0; ks < 4; ks++) {
      half8 a;
#pragma unroll
      for (int j = 0; j < 8; j++)
        a[j] = (half_t)xb[(size_t)(ks * 32 + quad * 8 + j) * 1024];
      afr[ks] = a;
    }
  }

  for (int op = 0; op < 3; op++) {
    int combo = op * 2 + hf;
    const half_t* wfb = wfrag + combo * 16384;
    float4v acc[4];
#pragma unroll
    for (int ngl = 0; ngl < 4; ngl++) {
      int ng = cw * 4 + ngl;
      float4v c = {0.f, 0.f, 0.f, 0.f};
#pragma unroll
      for (int ks = 0; ks < 4; ks++) {
        half8 bfrag =
            *(const half8*)(wfb + ((ng * 4 + ks) * 64 + lane) * 8);
        c = mfma16(afr[ks], bfrag, c);
      }
      acc[ngl] = c;
    }
#pragma unroll
    for (int ngl = 0; ngl < 4; ngl++) {
      float bb = bws[combo * 128 + (cw * 4 + ngl) * 16 + l];
#pragma unroll
      for (int r2 = 0; r2 < 4; r2++) acc[ngl][r2] += bb;
    }
    if (op < 2) {
      // normalize per head: this wave's heads = hf*4 + cw*2 + {0,1}
#pragma unroll
      for (int hgl = 0; hgl < 2; hgl++) {
        float sc = 1.0f;
        if (op == 0)
          sc = __expf(fminf(lscale[hf * 4 + cw * 2 + hgl], 4.6051702f)) *
               1.44269504f;
#pragma unroll
        for (int r2 = 0; r2 < 4; r2++) {
          float ss = acc[2 * hgl][r2] * acc[2 * hgl][r2] +
                     acc[2 * hgl + 1][r2] * acc[2 * hgl + 1][r2];
          ss += __shfl_xor(ss, 1, 64);
          ss += __shfl_xor(ss, 2, 64);
          ss += __shfl_xor(ss, 4, 64);
          ss += __shfl_xor(ss, 8, 64);
          float rn = sc / fmaxf(sqrtf(ss), 1e-12f);
          acc[2 * hgl][r2] *= rn;
          acc[2 * hgl + 1][r2] *= rn;
        }
      }
      // transpose via LDS [row32][col128] stride 136 -> coalesced half8
#pragma unroll
      for (int ngl = 0; ngl < 4; ngl++)
#pragma unroll
        for (int r2 = 0; r2 < 4; r2++)
          tbuf[(rw * 16 + quad * 4 + r2) * 136 + (cw * 4 + ngl) * 16 + l] =
              (half_t)acc[ngl][r2];
      __syncthreads();
      half_t* dst = (op == 0) ? qf : kf;
#pragma unroll
      for (int i = 0; i < 2; i++) {
        int idx = t + 256 * i;
        int row = idx >> 4, colc = (idx & 15) * 8;
        half8 vv = *(const half8*)(tbuf + row * 136 + colc);
        int head = hf * 4 + (colc >> 5), d = colc & 31;
        *(half8*)(dst + (((size_t)b * 8 + head) * 1024 + n0 + row) * 32 + d) =
            vv;
      }
      __syncthreads();
    } else {
      // v: [col128][row32] stride 36 -> coalesced dword to [b][h][d][n]
#pragma unroll
      for (int ngl = 0; ngl < 4; ngl++) {
        int col = (cw * 4 + ngl) * 16 + l;
        half4 hv;
#pragma unroll
        for (int r2 = 0; r2 < 4; r2++) hv[r2] = (half_t)acc[ngl][r2];
        *(half4*)(tbuf + col * 36 + rw * 16 + quad * 4) = hv;
      }
      __syncthreads();
#pragma unroll
      for (int i = 0; i < 8; i++) {
        int idx = t + 256 * i;
        int col = idx >> 4, rp = idx & 15;
        unsigned int val = *(const unsigned int*)(tbuf + col * 36 + rp * 2);
        int head = hf * 4 + (col >> 5);
        int d = col & 31;
        *(unsigned int*)((char*)vf +
                         (((((size_t)b * 8 + head) * 32 + d) * 1024) + n0 +
                          rp * 2) * 2) = val;
      }
    }
  }
}

// ---------------------------------------------------------------------------
// attn_mfma: barrier-free flash attention, XCD-local K/V.
// 1-D grid 1024: id = qo*128 + (b*8+h) -> the 8 qo-blocks of one (b,h) are
// congruent mod 8 -> same XCD -> K/V L2-resident.  256 thr (4 waves), wave
// owns 32 q-rows = one image row.  P~ = exp2(QK + biastab).
// ---------------------------------------------------------------------------
__global__ __launch_bounds__(256) void attn_mfma(
    const half_t* __restrict__ qf, const half_t* __restrict__ kf,
    const half_t* __restrict__ vf, const float* __restrict__ tabh2,
    half_t* __restrict__ ao) {
  __shared__ float sb2[35 * 63];      // bias slice: dih-local in [0,35)
  __shared__ half_t pa[4 * 16 * 80];  // per-wave P~ [qrow][key], stride 80

  int id = blockIdx.x;
  int qo = id >> 7;
  int bh = id & 127;
  int h = bh & 7, b = bh >> 3;
  int t = threadIdx.x;
  int lane = t & 63, wv = t >> 6, l = lane & 15, quad = lane >> 4;
  size_t bhs = (size_t)b * 8 + h;
  const half_t* kbase = kf + bhs * 1024 * 32;
  const half_t* vbase = vf + bhs * 32 * 1024;

  // stage bias slice: dih_global in [qo*4, qo*4+35)
  for (int i = t; i < 2205; i += 256)
    sb2[i] = tabh2[h * 3969 + qo * 252 + i];

  int row0 = qo * 128 + wv * 32;
  half8 qfr[2];
#pragma unroll
  for (int s = 0; s < 2; s++)
    qfr[s] = *(const half8*)(qf + (bhs * 1024 + row0 + s * 16 + l) * 32 +
                             quad * 8);

  float4v o0[2], o1[2];
  float run_l[2];
#pragma unroll
  for (int s = 0; s < 2; s++) {
    o0[s] = (float4v){0.f, 0.f, 0.f, 0.f};
    o1[s] = (float4v){0.f, 0.f, 0.f, 0.f};
    run_l[s] = 0.0f;
  }
  half_t* paw = pa + wv * 16 * 80;
  __syncthreads();  // the ONLY barrier

#pragma unroll 2
  for (int kt = 0; kt < 16; kt++) {
    half8 kfr[4], v0fr[2], v1fr[2];
#pragma unroll
    for (int nt = 0; nt < 4; nt++)
      kfr[nt] =
          *(const half8*)(kbase + (kt * 64 + nt * 16 + l) * 32 + quad * 8);
#pragma unroll
    for (int ks = 0; ks < 2; ks++) {
      v0fr[ks] = *(const half8*)(vbase + l * 1024 + kt * 64 + ks * 32 +
                                 quad * 8);
      v1fr[ks] = *(const half8*)(vbase + (16 + l) * 1024 + kt * 64 + ks * 32 +
                                 quad * 8);
    }
#pragma unroll
    for (int s = 0; s < 2; s++) {
      float4v sres[4];
#pragma unroll
      for (int nt = 0; nt < 4; nt++) {
        int base = (wv - 2 * kt - (nt >> 1) + 31) * 63 + s * 16 + l + 31 -
                   (nt & 1) * 16 - quad * 4;
        float4v c;
        c[0] = sb2[base];
        c[1] = sb2[base - 1];
        c[2] = sb2[base - 2];
        c[3] = sb2[base - 3];
        sres[nt] = mfma16(kfr[nt], qfr[s], c);
      }
#pragma unroll
      for (int nt = 0; nt < 4; nt++) {
        half4 ph;
#pragma unroll
        for (int r2 = 0; r2 < 4; r2++) {
          float p = exp2f(sres[nt][r2]);
          run_l[s] += p;
          ph[r2] = (half_t)p;
        }
        *(half4*)(paw + l * 80 + nt * 16 + quad * 4) = ph;
      }
#pragma unroll
      for (int ks = 0; ks < 2; ks++) {
        half8 pfr = *(const half8*)(paw + l * 80 + ks * 32 + quad * 8);
        o0[s] = mfma16(pfr, v0fr[ks], o0[s]);
        o1[s] = mfma16(pfr, v1fr[ks], o1[s]);
      }
    }
  }

#pragma unroll
  for (int s = 0; s < 2; s++) {
    float rl = run_l[s];
    rl += __shfl_xor(rl, 16, 64);
    rl += __shfl_xor(rl, 32, 64);
    float rli = 1.0f / rl;
#pragma unroll
    for (int r2 = 0; r2 < 4; r2++) {
      float linv = __shfl(rli, 20 * quad + r2, 64);
      size_t rowaddr =
          ((size_t)b * 1024 + row0 + s * 16 + quad * 4 + r2) * 256 + h * 32;
      ao[rowaddr + l] = (half_t)(o0[s][r2] * linv);
      ao[rowaddr + 16 + l] = (half_t)(o1[s][r2] * linv);
    }
  }
}

// ---------------------------------------------------------------------------
// proj_mfma: output projection, fp32 out [b][ch][n] via LDS transpose.
// grid (512 rowtiles-of-32, 2 hf) x 256.  W-frags direct from global.
// ---------------------------------------------------------------------------
__global__ __launch_bounds__(256, 4) void proj_mfma(
    const half_t* __restrict__ ao, const half_t* __restrict__ wfrag,
    const float* __restrict__ bws, float* __restrict__ out) {
  __shared__ float yt[128 * 36];
  int t = threadIdx.x;
  int lane = t & 63, wv = t >> 6, l = lane & 15, quad = lane >> 4;
  int rw = wv & 1, cw = wv >> 1;
  int hf = blockIdx.y;
  int m0 = blockIdx.x * 32;
  int b = m0 >> 10, n0 = m0 & 1023;

  half8 afr[4];
  const half_t* ab =
      ao + ((size_t)m0 + rw * 16 + l) * 256 + hf * 128 + quad * 8;
#pragma unroll
  for (int ks = 0; ks < 4; ks++) afr[ks] = *(const half8*)(ab + ks * 32);

  const half_t* wfb = wfrag + (6 + hf) * 16384;
#pragma unroll
  for (int ngl = 0; ngl < 4; ngl++) {
    int ng = cw * 4 + ngl;
    float4v c = {0.f, 0.f, 0.f, 0.f};
#pragma unroll
    for (int ks = 0; ks < 4; ks++) {
      half8 bfrag = *(const half8*)(wfb + ((ng * 4 + ks) * 64 + lane) * 8);
      c = mfma16(afr[ks], bfrag, c);
    }
    float bb = bws[(6 + hf) * 128 + ng * 16 + l];
#pragma unroll
    for (int r2 = 0; r2 < 4; r2++) c[r2] += bb;
    *(float4v*)(yt + (ng * 16 + l) * 36 + rw * 16 + quad * 4) = c;
  }
  __syncthreads();
#pragma unroll
  for (int i = 0; i < 4; i++) {
    int idx = t + 256 * i;
    int col = idx >> 3, rg = idx & 7;
    float4v vv = *(const float4v*)(yt + col * 36 + rg * 4);
    *(float4v*)(out + ((size_t)b * 256 + hf * 128 + col) * 1024 + n0 +
                rg * 4) = vv;
  }
}

// ---------------------------------------------------------------------------
extern "C" void kernel_launch(void* const* d_in, const int* in_sizes, int n_in,
                              void* d_out, int out_size, void* d_ws,
                              size_t ws_size, hipStream_t stream) {
  (void)in_sizes; (void)n_in; (void)out_size; (void)ws_size;
  const float* x = (const float*)d_in[0];

  half_t* ws = (half_t*)d_ws;
  half_t* qfp = ws;                    // [16][8][1024][32] f16
  half_t* kfp = ws + 4194304;          // [16][8][1024][32] f16
  half_t* vfp = ws + 8388608;          // [16][8][32][1024] f16 (transposed)
  half_t* aop = ws + 12582912;         // [16384][256] f16
  half_t* wfp = ws + 16777216;         // 8 x 16384 f16, fragment layout
  float* tabh2 = (float*)((char*)d_ws + 33816576);  // [8][3969] f32
  float* bws = (float*)((char*)d_ws + 33943584);    // [8][128] f32

  PtrArr8 wsrc, bsrc;
  const int widx[8] = {1, 3, 5, 7, 9, 11, 13, 15};
  for (int i = 0; i < 8; i++) {
    wsrc.p[i] = (const float*)d_in[widx[i]];
    bsrc.p[i] = (const float*)d_in[widx[i] + 1];
  }

  prep_w<<<dim3(16, 8), 256, 0, stream>>>(wsrc, bsrc, wfp, bws);
  bias_mlp<<<16, 256, 0, stream>>>((const float*)d_in[18],
                                   (const float*)d_in[19],
                                   (const float*)d_in[20],
                                   (const float*)d_in[17], tabh2);
  qkv_mfma<<<dim3(512, 2), 256, 0, stream>>>(x, wfp, (const float*)d_in[17],
                                             bws, qfp, kfp, vfp);
  attn_mfma<<<1024, 256, 0, stream>>>(qfp, kfp, vfp, tabh2, aop);
  proj_mfma<<<dim3(512, 2), 256, 0, stream>>>(aop, wfp, bws, (float*)d_out);
}